// Round 15
// baseline (265.654 us; speedup 1.0000x reference)
//
#include <hip/hip_runtime.h>
#include <hip/hip_fp16.h>

// Volume rotate + trilinear resample + projection along axis 2.
// Round-12 (4th attempt; three infra failures, experiment still unmeasured):
// (a) pack kernel rewritten for coalesced brick writes (LDS-staged, one
// contiguous 512B chunk per wave-store); (b) XCD-aware block swizzle in the
// main kernel for L2 gather-line sharing. Math/layout otherwise identical to
// round 11 (fp16 4-corner granules in 8x8x8-voxel bricks, 2 gathers/sample,
// 4x4x4 wave sample-bricks, pixel-space ray constants).
//
// granule(z,y,x) = (V[z,y,x],V[z,y,x1],V[z,y1,x],V[z,y1,x1]) as 4xfp16, 8B.
// brick index: ((z>>3)<<19)|((y>>3)<<14)|((x>>3)<<9)|((z&7)<<6)|((y&7)<<3)|(x&7)

#define NN 256

// ---------------- helpers ----------------

__device__ __forceinline__ unsigned pack2h(float lo, float hi) {
    __half2 h = __floats2half2_rn(lo, hi);
    return *reinterpret_cast<unsigned*>(&h);
}

__device__ __forceinline__ float2 unpack2h(unsigned u) {
    __half2 h = *reinterpret_cast<__half2*>(&u);
    return __half22float2(h);
}

// ---------------- pack kernel (LDS-staged, coalesced brick writes) --------
// Block = (z-brick zb, y-brick yb). Per z-slice: stage 9 vol rows (256 fl)
// in LDS, then each wave emits 8 chunks of 64 granules; chunk = fixed x-brick,
// lane l -> (y7=l>>3, x7=l&7) so the 64x8B store is 512B contiguous.

__global__ __launch_bounds__(256) void packbrick_kernel(
    const float* __restrict__ vol, uint2* __restrict__ v4)
{
    __shared__ float rows[9][260];   // 260-pad: 2-way-max LDS bank aliasing

    const int zb = blockIdx.x >> 5;     // 0..31
    const int yb = blockIdx.x & 31;     // 0..31
    const int tid = threadIdx.x;
    const int w = tid >> 6;             // wave 0..3
    const int l = tid & 63;             // lane
    const int y7 = l >> 3;
    const int x7 = l & 7;

    for (int z7 = 0; z7 < 8; ++z7) {
        const int z = (zb << 3) | z7;

        __syncthreads();   // rows from previous slice fully consumed
        for (int r = tid; r < 576; r += 256) {          // 9 rows x 64 float4
            const int row = r >> 6;
            const int xg = (r & 63) << 2;
            const int y = min((yb << 3) + row, NN - 1);
            const float4 v = *reinterpret_cast<const float4*>(
                vol + ((z << 16) | (y << 8) | xg));
            *reinterpret_cast<float4*>(&rows[row][xg]) = v;
        }
        __syncthreads();

        const int base = (zb << 19) | (yb << 14) | (z7 << 6);
#pragma unroll
        for (int xi = 0; xi < 8; ++xi) {
            const int xb = (xi << 2) | w;               // 0..31
            const int x = (xb << 3) | x7;
            const int xp = min(x + 1, NN - 1);
            const float v00 = rows[y7][x],     v01 = rows[y7][xp];
            const float v10 = rows[y7 + 1][x], v11 = rows[y7 + 1][xp];
            uint2 g;
            g.x = pack2h(v00, v01);
            g.y = pack2h(v10, v11);
            v4[base | (xb << 9) | l] = g;               // 512B/wave contiguous
        }
    }
}

// ---------------- geometry ----------------
// Pixel-space ray constants (continuity-safe; see round-8 derivation).

struct RayCtx {
    float bPx, bPy, bPz;    // pixel-space base
    float dPx, dPy, dPz;    // pixel-space k-direction
};

__device__ __forceinline__ RayCtx make_ray(const float* __restrict__ quats,
                                           int b, int i, int j)
{
    const float q0 = quats[b * 4 + 0];
    const float q1 = quats[b * 4 + 1];
    const float q2 = quats[b * 4 + 2];
    const float q3 = quats[b * 4 + 3];
    const float nrm = sqrtf(q0 * q0 + q1 * q1 + q2 * q2 + q3 * q3);
    const float qw = q0 / nrm, qx = q1 / nrm, qy = q2 / nrm, qz = q3 / nrm;

    const float r00 = 1.0f - 2.0f * (qy * qy + qz * qz);
    const float r01 = 2.0f * (qx * qy - qz * qw);
    const float r02 = 2.0f * (qx * qz + qy * qw);
    const float r10 = 2.0f * (qx * qy + qz * qw);
    const float r11 = 1.0f - 2.0f * (qx * qx + qz * qz);
    const float r12 = 2.0f * (qy * qz - qx * qw);
    const float r20 = 2.0f * (qx * qz - qy * qw);
    const float r21 = 2.0f * (qy * qz + qx * qw);
    const float r22 = 1.0f - 2.0f * (qx * qx + qy * qy);

    const float gi = (float)i - 128.0f;
    const float gj = (float)j - 128.0f;

    const float bx = gi * r00 + gj * r01;
    const float by = gi * r10 + gj * r11;
    const float bz = gi * r20 + gj * r21;

    const float K = 127.5f / 128.0f;   // exact fp32
    RayCtx c;
    c.dPx = r02 * K;  c.dPy = r12 * K;  c.dPz = r22 * K;
    c.bPx = bx * K + 127.5f;
    c.bPy = by * K + 127.5f;
    c.bPz = bz * K + 127.5f;
    return c;
}

// ---------------- main kernel: 4x4x4 lane bricks, 2 gathers/sample ----------
// 1D grid of 1024*B blocks, XCD-swizzled: hardware block h (round-robin
// h%8 -> XCD) maps to logical wg = (h%8)*(nwg/8) + h/8, so each XCD gets a
// contiguous chunk of the (b, i-tile, j-tile) ordering -> neighbor tiles
// share gather cache lines within one XCD's L2.

__global__ __launch_bounds__(256) void rotproj4hb_kernel(
    const uint2* __restrict__ v4,
    const float* __restrict__ quats,
    float* __restrict__ out)
{
    const int q8 = gridDim.x >> 3;
    const int wg = (blockIdx.x & 7) * q8 + (blockIdx.x >> 3);
    const int b = wg >> 10;
    const int by = (wg >> 5) & 31;
    const int bx = wg & 31;

    const int tid = threadIdx.x;
    const int w = tid >> 6;
    const int l = tid & 63;
    const int di = l & 3;
    const int dj = (l >> 2) & 3;
    const int dk = l >> 4;

    const int i = (by << 3) + ((w & 1) << 2) + di;
    const int j = (bx << 3) + ((w >> 1) << 2) + dj;

    const RayCtx c = make_ray(quats, b, i, j);

    float acc = 0.0f;
    float kf = (float)dk - 128.0f;   // gk for k = 4t+dk; exact integer steps

#pragma unroll 8
    for (int t = 0; t < 64; ++t) {
        float px = fminf(fmaxf(fmaf(kf, c.dPx, c.bPx), 0.0f), 255.0f);
        float py = fminf(fmaxf(fmaf(kf, c.dPy, c.bPy), 0.0f), 255.0f);
        float pz = fminf(fmaxf(fmaf(kf, c.dPz, c.bPz), 0.0f), 255.0f);
        kf += 4.0f;

        const int x0 = (int)px;                 // trunc == floor (px >= 0)
        const int y0 = (int)py;
        const int z0 = (int)pz;
        const float tfx = __builtin_amdgcn_fractf(px);
        const float tfy = __builtin_amdgcn_fractf(py);
        const float tfz = __builtin_amdgcn_fractf(pz);
        const int z1 = z0 + (z0 < NN - 1 ? 1 : 0);

        // brick-layout addresses (y/x part shared between the two gathers)
        const int yx = ((y0 >> 3) << 14) | ((x0 >> 3) << 9)
                     | ((y0 & 7) << 3)  | (x0 & 7);
        const int za = ((z0 >> 3) << 19) | ((z0 & 7) << 6);
        const int zd = ((z1 >> 3) << 19) | ((z1 & 7) << 6);

        const uint2 A = v4[yx | za];
        const uint2 D = v4[yx | zd];

        const float2 a0 = unpack2h(A.x);   // (z0,y0,x0), (z0,y0,x1)
        const float2 a1 = unpack2h(A.y);   // (z0,y1,x0), (z0,y1,x1)
        const float2 d0 = unpack2h(D.x);   // (z1,y0,*)
        const float2 d1 = unpack2h(D.y);   // (z1,y1,*)

        const float ux = 1.0f - tfx, uy = 1.0f - tfy, uz = 1.0f - tfz;
        const float c00 = a0.x * ux + a0.y * tfx;
        const float c01 = a1.x * ux + a1.y * tfx;
        const float c10 = d0.x * ux + d0.y * tfx;
        const float c11 = d1.x * ux + d1.y * tfx;
        const float c0 = c00 * uy + c01 * tfy;
        const float c1 = c10 * uy + c11 * tfy;
        acc += c0 * uz + c1 * tfz;
    }

    // fold the 4 k-residue partials (lanes differing in dk = bits 4,5)
    acc += __shfl_xor(acc, 16, 64);
    acc += __shfl_xor(acc, 32, 64);
    if (dk == 0) {
        out[(b << 16) | (i << 8) | j] = acc;
    }
}

// ---------------- direct fallback (proven path) ----------------

__global__ __launch_bounds__(256) void rotproj_direct_kernel(
    const float* __restrict__ vol,
    const float* __restrict__ quats,
    float* __restrict__ out)
{
    const int tx = threadIdx.x & 7;
    const int ty = (threadIdx.x >> 3) & 7;
    const int tz = threadIdx.x >> 6;
    const int b = blockIdx.z;
    const int i = blockIdx.y * 8 + ty;
    const int j = blockIdx.x * 8 + tx;

    const RayCtx c = make_ray(quats, b, i, j);

    float acc = 0.0f;
    float kf = (float)(tz * 64) - 128.0f;
#pragma unroll 4
    for (int kk = 0; kk < 64; ++kk) {
        float px = fminf(fmaxf(fmaf(kf, c.dPx, c.bPx), 0.0f), 255.0f);
        float py = fminf(fmaxf(fmaf(kf, c.dPy, c.bPy), 0.0f), 255.0f);
        float pz = fminf(fmaxf(fmaf(kf, c.dPz, c.bPz), 0.0f), 255.0f);
        kf += 1.0f;

        const int x0 = (int)px, y0 = (int)py, z0 = (int)pz;
        const float tfx = __builtin_amdgcn_fractf(px);
        const float tfy = __builtin_amdgcn_fractf(py);
        const float tfz = __builtin_amdgcn_fractf(pz);
        const int x1 = min(x0 + 1, NN - 1);
        const int y1 = min(y0 + 1, NN - 1);
        const int z1 = min(z0 + 1, NN - 1);

        const float* row00 = vol + ((z0 << 16) | (y0 << 8));
        const float* row01 = vol + ((z0 << 16) | (y1 << 8));
        const float* row10 = vol + ((z1 << 16) | (y0 << 8));
        const float* row11 = vol + ((z1 << 16) | (y1 << 8));

        const float v000 = row00[x0], v001 = row00[x1];
        const float v010 = row01[x0], v011 = row01[x1];
        const float v100 = row10[x0], v101 = row10[x1];
        const float v110 = row11[x0], v111 = row11[x1];

        const float ux = 1.0f - tfx, uy = 1.0f - tfy, uz = 1.0f - tfz;
        const float c00 = v000 * ux + v001 * tfx;
        const float c01 = v010 * ux + v011 * tfx;
        const float c10 = v100 * ux + v101 * tfx;
        const float c11 = v110 * ux + v111 * tfx;
        const float c0 = c00 * uy + c01 * tfy;
        const float c1 = c10 * uy + c11 * tfy;
        acc += c0 * uz + c1 * tfz;
    }

    __shared__ float sm[4][8][8];
    sm[tz][ty][tx] = acc;
    __syncthreads();
    if (tz == 0) {
        out[(b << 16) | (i << 8) | j] =
            sm[0][ty][tx] + sm[1][ty][tx] + sm[2][ty][tx] + sm[3][ty][tx];
    }
}

// ---------------- launch ----------------

extern "C" void kernel_launch(void* const* d_in, const int* in_sizes, int n_in,
                              void* d_out, int out_size, void* d_ws, size_t ws_size,
                              hipStream_t stream) {
    const float* vol = (const float*)d_in[0];
    const float* quats = (const float*)d_in[1];
    float* out = (float*)d_out;

    const int B = in_sizes[1] / 4;  // quaternions: (B,4)
    const size_t nvox = (size_t)NN * NN * NN;
    const size_t need = nvox * sizeof(uint2);   // 134 MB

    if (ws_size >= need) {
        uint2* v4 = (uint2*)d_ws;
        hipLaunchKernelGGL(packbrick_kernel, dim3(1024), dim3(256), 0, stream,
                           vol, v4);
        hipLaunchKernelGGL(rotproj4hb_kernel, dim3(1024 * B), dim3(256), 0,
                           stream, v4, quats, out);
    } else {
        dim3 grid(NN / 8, NN / 8, B);
        hipLaunchKernelGGL(rotproj_direct_kernel, grid, dim3(256), 0, stream,
                           vol, quats, out);
    }
}

// Round 16
// 246.254 us; speedup vs baseline: 1.0788x; 1.0788x over previous
//
#include <hip/hip_runtime.h>
#include <hip/hip_fp16.h>

// Volume rotate + trilinear resample + projection along axis 2.
// Round-16: REVERT the XCD swizzle (r15 measured: FETCH -10% but service
// rate 2.76->2.15 TB/s, main 132->152 us — temporal convergence of the whole
// machine on one region beats per-XCD partitioning for this gather). Keep the
// LDS coalesced pack (neutral-to-slightly-better). NEW: 2 rays per thread
// (8x16 block tile, thread owns j and j+8): 4 gathers in flight per k-step,
// block footprint shared by both sub-rays in L2.
//
// granule(z,y,x) = (V[z,y,x],V[z,y,x1],V[z,y1,x],V[z,y1,x1]) as 4xfp16, 8B.
// brick index: ((z>>3)<<19)|((y>>3)<<14)|((x>>3)<<9)|((z&7)<<6)|((y&7)<<3)|(x&7)

#define NN 256

// ---------------- helpers ----------------

__device__ __forceinline__ unsigned pack2h(float lo, float hi) {
    __half2 h = __floats2half2_rn(lo, hi);
    return *reinterpret_cast<unsigned*>(&h);
}

__device__ __forceinline__ float2 unpack2h(unsigned u) {
    __half2 h = *reinterpret_cast<__half2*>(&u);
    return __half22float2(h);
}

// ---------------- pack kernel (LDS-staged, coalesced brick writes) --------

__global__ __launch_bounds__(256) void packbrick_kernel(
    const float* __restrict__ vol, uint2* __restrict__ v4)
{
    __shared__ float rows[9][260];

    const int zb = blockIdx.x >> 5;     // 0..31
    const int yb = blockIdx.x & 31;     // 0..31
    const int tid = threadIdx.x;
    const int w = tid >> 6;
    const int l = tid & 63;
    const int y7 = l >> 3;
    const int x7 = l & 7;

    for (int z7 = 0; z7 < 8; ++z7) {
        const int z = (zb << 3) | z7;

        __syncthreads();
        for (int r = tid; r < 576; r += 256) {          // 9 rows x 64 float4
            const int row = r >> 6;
            const int xg = (r & 63) << 2;
            const int y = min((yb << 3) + row, NN - 1);
            const float4 v = *reinterpret_cast<const float4*>(
                vol + ((z << 16) | (y << 8) | xg));
            *reinterpret_cast<float4*>(&rows[row][xg]) = v;
        }
        __syncthreads();

        const int base = (zb << 19) | (yb << 14) | (z7 << 6);
#pragma unroll
        for (int xi = 0; xi < 8; ++xi) {
            const int xb = (xi << 2) | w;               // 0..31
            const int x = (xb << 3) | x7;
            const int xp = min(x + 1, NN - 1);
            const float v00 = rows[y7][x],     v01 = rows[y7][xp];
            const float v10 = rows[y7 + 1][x], v11 = rows[y7 + 1][xp];
            uint2 g;
            g.x = pack2h(v00, v01);
            g.y = pack2h(v10, v11);
            v4[base | (xb << 9) | l] = g;               // 512B/wave contiguous
        }
    }
}

// ---------------- main kernel: 2 rays/thread, 2 gathers/sample ----------
// Grid (16,32,B), block 256. Tile = 8 (i) x 16 (j). Wave w: i-quad (w&1)*4,
// j-quad (w>>1)*4; lane: di=l&3, dj=(l>>2)&3, dk=l>>4 (k residue).
// Thread rays: (i, j0) and (i, j0+8). Fold dk via shfl_xor(16|32).

__global__ __launch_bounds__(256) void rotproj4hb_kernel(
    const uint2* __restrict__ v4,
    const float* __restrict__ quats,
    float* __restrict__ out)
{
    const int tid = threadIdx.x;
    const int w = tid >> 6;
    const int l = tid & 63;
    const int di = l & 3;
    const int dj = (l >> 2) & 3;
    const int dk = l >> 4;

    const int b = blockIdx.z;
    const int i  = (blockIdx.y << 3) + ((w & 1) << 2) + di;
    const int j0 = (blockIdx.x << 4) + ((w >> 1) << 2) + dj;
    const int j1 = j0 + 8;

    // --- quaternion -> rotation (reference numerics) ---
    const float q0 = quats[b * 4 + 0];
    const float q1 = quats[b * 4 + 1];
    const float q2 = quats[b * 4 + 2];
    const float q3 = quats[b * 4 + 3];
    const float nrm = sqrtf(q0 * q0 + q1 * q1 + q2 * q2 + q3 * q3);
    const float qw = q0 / nrm, qx = q1 / nrm, qy = q2 / nrm, qz = q3 / nrm;

    const float r00 = 1.0f - 2.0f * (qy * qy + qz * qz);
    const float r01 = 2.0f * (qx * qy - qz * qw);
    const float r02 = 2.0f * (qx * qz + qy * qw);
    const float r10 = 2.0f * (qx * qy + qz * qw);
    const float r11 = 1.0f - 2.0f * (qx * qx + qz * qz);
    const float r12 = 2.0f * (qy * qz - qx * qw);
    const float r20 = 2.0f * (qx * qz - qy * qw);
    const float r21 = 2.0f * (qy * qz + qx * qw);
    const float r22 = 1.0f - 2.0f * (qx * qx + qy * qy);

    const float gi  = (float)i  - 128.0f;
    const float gj0 = (float)j0 - 128.0f;
    const float gj1 = (float)j1 - 128.0f;

    const float K = 127.5f / 128.0f;   // exact fp32
    const float dPx = r02 * K, dPy = r12 * K, dPz = r22 * K;
    const float b0x = (gi * r00 + gj0 * r01) * K + 127.5f;
    const float b0y = (gi * r10 + gj0 * r11) * K + 127.5f;
    const float b0z = (gi * r20 + gj0 * r21) * K + 127.5f;
    const float b1x = (gi * r00 + gj1 * r01) * K + 127.5f;
    const float b1y = (gi * r10 + gj1 * r11) * K + 127.5f;
    const float b1z = (gi * r20 + gj1 * r21) * K + 127.5f;

    float acc0 = 0.0f, acc1 = 0.0f;
    float kf = (float)dk - 128.0f;   // k = 4t+dk; exact integer steps

#pragma unroll 4
    for (int t = 0; t < 64; ++t) {
        // ---- ray 0 coords ----
        float px0 = fminf(fmaxf(fmaf(kf, dPx, b0x), 0.0f), 255.0f);
        float py0 = fminf(fmaxf(fmaf(kf, dPy, b0y), 0.0f), 255.0f);
        float pz0 = fminf(fmaxf(fmaf(kf, dPz, b0z), 0.0f), 255.0f);
        // ---- ray 1 coords ----
        float px1 = fminf(fmaxf(fmaf(kf, dPx, b1x), 0.0f), 255.0f);
        float py1 = fminf(fmaxf(fmaf(kf, dPy, b1y), 0.0f), 255.0f);
        float pz1 = fminf(fmaxf(fmaf(kf, dPz, b1z), 0.0f), 255.0f);
        kf += 4.0f;

        const int x0a = (int)px0, y0a = (int)py0, z0a = (int)pz0;
        const int x0b = (int)px1, y0b = (int)py1, z0b = (int)pz1;
        const float tfx0 = __builtin_amdgcn_fractf(px0);
        const float tfy0 = __builtin_amdgcn_fractf(py0);
        const float tfz0 = __builtin_amdgcn_fractf(pz0);
        const float tfx1 = __builtin_amdgcn_fractf(px1);
        const float tfy1 = __builtin_amdgcn_fractf(py1);
        const float tfz1 = __builtin_amdgcn_fractf(pz1);
        const int z1a = z0a + (z0a < NN - 1 ? 1 : 0);
        const int z1b = z0b + (z0b < NN - 1 ? 1 : 0);

        // brick addresses
        const int yxa = ((y0a >> 3) << 14) | ((x0a >> 3) << 9)
                      | ((y0a & 7) << 3)  | (x0a & 7);
        const int yxb = ((y0b >> 3) << 14) | ((x0b >> 3) << 9)
                      | ((y0b & 7) << 3)  | (x0b & 7);

        const uint2 A0 = v4[yxa | ((z0a >> 3) << 19) | ((z0a & 7) << 6)];
        const uint2 D0 = v4[yxa | ((z1a >> 3) << 19) | ((z1a & 7) << 6)];
        const uint2 A1 = v4[yxb | ((z0b >> 3) << 19) | ((z0b & 7) << 6)];
        const uint2 D1 = v4[yxb | ((z1b >> 3) << 19) | ((z1b & 7) << 6)];

        // ---- ray 0 lerp ----
        {
            const float2 a0 = unpack2h(A0.x), a1 = unpack2h(A0.y);
            const float2 d0 = unpack2h(D0.x), d1 = unpack2h(D0.y);
            const float ux = 1.0f - tfx0, uy = 1.0f - tfy0, uz = 1.0f - tfz0;
            const float c00 = a0.x * ux + a0.y * tfx0;
            const float c01 = a1.x * ux + a1.y * tfx0;
            const float c10 = d0.x * ux + d0.y * tfx0;
            const float c11 = d1.x * ux + d1.y * tfx0;
            const float c0 = c00 * uy + c01 * tfy0;
            const float c1 = c10 * uy + c11 * tfy0;
            acc0 += c0 * uz + c1 * tfz0;
        }
        // ---- ray 1 lerp ----
        {
            const float2 a0 = unpack2h(A1.x), a1 = unpack2h(A1.y);
            const float2 d0 = unpack2h(D1.x), d1 = unpack2h(D1.y);
            const float ux = 1.0f - tfx1, uy = 1.0f - tfy1, uz = 1.0f - tfz1;
            const float c00 = a0.x * ux + a0.y * tfx1;
            const float c01 = a1.x * ux + a1.y * tfx1;
            const float c10 = d0.x * ux + d0.y * tfx1;
            const float c11 = d1.x * ux + d1.y * tfx1;
            const float c0 = c00 * uy + c01 * tfy1;
            const float c1 = c10 * uy + c11 * tfy1;
            acc1 += c0 * uz + c1 * tfz1;
        }
    }

    // fold the 4 k-residue partials (lanes differing in dk = bits 4,5)
    acc0 += __shfl_xor(acc0, 16, 64);
    acc0 += __shfl_xor(acc0, 32, 64);
    acc1 += __shfl_xor(acc1, 16, 64);
    acc1 += __shfl_xor(acc1, 32, 64);
    if (dk == 0) {
        out[(b << 16) | (i << 8) | j0] = acc0;
        out[(b << 16) | (i << 8) | j1] = acc1;
    }
}

// ---------------- direct fallback (proven path) ----------------

struct RayCtx {
    float bPx, bPy, bPz;
    float dPx, dPy, dPz;
};

__device__ __forceinline__ RayCtx make_ray(const float* __restrict__ quats,
                                           int b, int i, int j)
{
    const float q0 = quats[b * 4 + 0];
    const float q1 = quats[b * 4 + 1];
    const float q2 = quats[b * 4 + 2];
    const float q3 = quats[b * 4 + 3];
    const float nrm = sqrtf(q0 * q0 + q1 * q1 + q2 * q2 + q3 * q3);
    const float qw = q0 / nrm, qx = q1 / nrm, qy = q2 / nrm, qz = q3 / nrm;

    const float r00 = 1.0f - 2.0f * (qy * qy + qz * qz);
    const float r01 = 2.0f * (qx * qy - qz * qw);
    const float r02 = 2.0f * (qx * qz + qy * qw);
    const float r10 = 2.0f * (qx * qy + qz * qw);
    const float r11 = 1.0f - 2.0f * (qx * qx + qz * qz);
    const float r12 = 2.0f * (qy * qz - qx * qw);
    const float r20 = 2.0f * (qx * qz - qy * qw);
    const float r21 = 2.0f * (qy * qz + qx * qw);
    const float r22 = 1.0f - 2.0f * (qx * qx + qy * qy);

    const float gi = (float)i - 128.0f;
    const float gj = (float)j - 128.0f;

    const float bx = gi * r00 + gj * r01;
    const float by = gi * r10 + gj * r11;
    const float bz = gi * r20 + gj * r21;

    const float K = 127.5f / 128.0f;
    RayCtx c;
    c.dPx = r02 * K;  c.dPy = r12 * K;  c.dPz = r22 * K;
    c.bPx = bx * K + 127.5f;
    c.bPy = by * K + 127.5f;
    c.bPz = bz * K + 127.5f;
    return c;
}

__global__ __launch_bounds__(256) void rotproj_direct_kernel(
    const float* __restrict__ vol,
    const float* __restrict__ quats,
    float* __restrict__ out)
{
    const int tx = threadIdx.x & 7;
    const int ty = (threadIdx.x >> 3) & 7;
    const int tz = threadIdx.x >> 6;
    const int b = blockIdx.z;
    const int i = blockIdx.y * 8 + ty;
    const int j = blockIdx.x * 8 + tx;

    const RayCtx c = make_ray(quats, b, i, j);

    float acc = 0.0f;
    float kf = (float)(tz * 64) - 128.0f;
#pragma unroll 4
    for (int kk = 0; kk < 64; ++kk) {
        float px = fminf(fmaxf(fmaf(kf, c.dPx, c.bPx), 0.0f), 255.0f);
        float py = fminf(fmaxf(fmaf(kf, c.dPy, c.bPy), 0.0f), 255.0f);
        float pz = fminf(fmaxf(fmaf(kf, c.dPz, c.bPz), 0.0f), 255.0f);
        kf += 1.0f;

        const int x0 = (int)px, y0 = (int)py, z0 = (int)pz;
        const float tfx = __builtin_amdgcn_fractf(px);
        const float tfy = __builtin_amdgcn_fractf(py);
        const float tfz = __builtin_amdgcn_fractf(pz);
        const int x1 = min(x0 + 1, NN - 1);
        const int y1 = min(y0 + 1, NN - 1);
        const int z1 = min(z0 + 1, NN - 1);

        const float* row00 = vol + ((z0 << 16) | (y0 << 8));
        const float* row01 = vol + ((z0 << 16) | (y1 << 8));
        const float* row10 = vol + ((z1 << 16) | (y0 << 8));
        const float* row11 = vol + ((z1 << 16) | (y1 << 8));

        const float v000 = row00[x0], v001 = row00[x1];
        const float v010 = row01[x0], v011 = row01[x1];
        const float v100 = row10[x0], v101 = row10[x1];
        const float v110 = row11[x0], v111 = row11[x1];

        const float ux = 1.0f - tfx, uy = 1.0f - tfy, uz = 1.0f - tfz;
        const float c00 = v000 * ux + v001 * tfx;
        const float c01 = v010 * ux + v011 * tfx;
        const float c10 = v100 * ux + v101 * tfx;
        const float c11 = v110 * ux + v111 * tfx;
        const float c0 = c00 * uy + c01 * tfy;
        const float c1 = c10 * uy + c11 * tfy;
        acc += c0 * uz + c1 * tfz;
    }

    __shared__ float sm[4][8][8];
    sm[tz][ty][tx] = acc;
    __syncthreads();
    if (tz == 0) {
        out[(b << 16) | (i << 8) | j] =
            sm[0][ty][tx] + sm[1][ty][tx] + sm[2][ty][tx] + sm[3][ty][tx];
    }
}

// ---------------- launch ----------------

extern "C" void kernel_launch(void* const* d_in, const int* in_sizes, int n_in,
                              void* d_out, int out_size, void* d_ws, size_t ws_size,
                              hipStream_t stream) {
    const float* vol = (const float*)d_in[0];
    const float* quats = (const float*)d_in[1];
    float* out = (float*)d_out;

    const int B = in_sizes[1] / 4;  // quaternions: (B,4)
    const size_t nvox = (size_t)NN * NN * NN;
    const size_t need = nvox * sizeof(uint2);   // 134 MB

    if (ws_size >= need) {
        uint2* v4 = (uint2*)d_ws;
        hipLaunchKernelGGL(packbrick_kernel, dim3(1024), dim3(256), 0, stream,
                           vol, v4);
        hipLaunchKernelGGL(rotproj4hb_kernel, dim3(16, 32, B), dim3(256), 0,
                           stream, v4, quats, out);
    } else {
        dim3 grid(NN / 8, NN / 8, B);
        hipLaunchKernelGGL(rotproj_direct_kernel, grid, dim3(256), 0, stream,
                           vol, quats, out);
    }
}